// Round 6
// baseline (189.012 us; speedup 1.0000x reference)
//
#include <hip/hip_runtime.h>
#include <hip/hip_bf16.h>
#include <math.h>

// MMD loss, N=8192 D=128 fp32 in, scalar fp32 out.
// Numerics (validated R1-R5, absmax 0): reference's (sum(Kxx)-trace) cancels to
// exactly 0 in fp32; answer = -2*S_xy/N^2 via emulated fp32 absorption. bf16
// MFMA gives approx d2; d2<140 -> exact fp32 re-dot (rare); 140..170 -> approx
// exp; else skip. All terms scaled e^{+128} -> fp32 accumulators.
//
// R6: K=128 makes LDS-staged GEMM structurally latency-bound (one K-iter; R5:
// 65% idle). New flatmm-style structure: A band (64 rows x full K) resident in
// 64 VGPRs, B streamed 32-col strips straight from L2 into mfma operands
// (row=lane&31, k-half=lane>>5 gather). 32x32x16 MFMA. No LDS tiles, no
// syncthreads in hot path; 3 waves/SIMD hide L2 latency.

#define NPTS 8192
#define DDIM 128
#define NBLK 2080   // 528 xx + 528 yy + 1024 xy  (256-row superband x 256-col chunk)

typedef __bf16 bf16x8 __attribute__((ext_vector_type(8)));
typedef float f32x16 __attribute__((ext_vector_type(16)));

// ws layout:
//   0       : double part[2080]   (16640 B per-block partials, scaled e^{+128})
//   16896   : float x2[8192]
//   49664   : float y2[8192]
//   82432   : __bf16 Zb [8192*128]  (2 MB)
//   2179584 : __bf16 Zpb[8192*128]  (2 MB)
__global__ void prep_kernel(const float* __restrict__ Z, const float* __restrict__ Zp,
                            float* __restrict__ x2, float* __restrict__ y2,
                            __bf16* __restrict__ Zb, __bf16* __restrict__ Zpb) {
    const int row = blockIdx.x * 16 + (threadIdx.x >> 4);   // 0..16383
    const int sub = threadIdx.x & 15;
    const float* src; float* nrm; __bf16* dst; int r;
    if (row < NPTS) { src = Z;  nrm = x2; dst = Zb;  r = row; }
    else            { src = Zp; nrm = y2; dst = Zpb; r = row - NPTS; }
    const float4* p = (const float4*)(src + (size_t)r * DDIM) + sub * 2;
    float4 a = p[0], b = p[1];
    float s = a.x*a.x + a.y*a.y + a.z*a.z + a.w*a.w
            + b.x*b.x + b.y*b.y + b.z*b.z + b.w*b.w;
    bf16x8 o = { (__bf16)a.x, (__bf16)a.y, (__bf16)a.z, (__bf16)a.w,
                 (__bf16)b.x, (__bf16)b.y, (__bf16)b.z, (__bf16)b.w };
    *(bf16x8*)(dst + (size_t)r * DDIM + sub * 8) = o;
    #pragma unroll
    for (int off = 8; off; off >>= 1) s += __shfl_down(s, off, 16);
    if (sub == 0) nrm[r] = s;
}

__launch_bounds__(256, 3)
__global__ void mmd_gemm(const float* __restrict__ Z, const float* __restrict__ Zp,
                         const __bf16* __restrict__ Zb, const __bf16* __restrict__ Zpb,
                         const float* __restrict__ x2g, const float* __restrict__ y2g,
                         double* __restrict__ part) {
    // ---- decode block -> (mat, sr, ck): superband sr (256 rows), chunk ck (256 cols)
    const int bid = blockIdx.x;
    int mat, sr, ck;
    if (bid < 1056) {
        mat = (bid < 528) ? 0 : 1;
        int idx = bid - mat * 528;
        int r = (int)((sqrtf(8.f * (float)idx + 1.f) - 1.f) * 0.5f);
        while ((r + 1) * (r + 2) / 2 <= idx) ++r;
        while (r * (r + 1) / 2 > idx) --r;
        sr = idx - r * (r + 1) / 2;     // sr <= ck: upper triangle
        ck = r;
    } else {
        mat = 2;
        int idx = bid - 1056;
        sr = idx >> 5; ck = idx & 31;
    }
    const float*  Xf = (mat == 1) ? Zp  : Z;
    const float*  Yf = (mat == 0) ? Z   : Zp;
    const __bf16* Xb = (mat == 1) ? Zpb : Zb;
    const __bf16* Yb = (mat == 0) ? Zb  : Zpb;
    const float*  xn = (mat == 1) ? y2g : x2g;
    const float*  yn = (mat == 0) ? x2g : y2g;

    const int tid = threadIdx.x, wv = tid >> 6, lane = tid & 63;
    const int lrow = lane & 31, lhalf = lane >> 5;
    const int R0 = sr * 256 + wv * 64;        // this wave's 64-row A band

    // ---- A band resident: 16 frags (2 row-halves x 8 k-steps) = 64 VGPRs
    bf16x8 a[2][8];
    {
        const __bf16* Ab = Xb + (size_t)R0 * DDIM + (size_t)lrow * DDIM + lhalf * 8;
        #pragma unroll
        for (int fm = 0; fm < 2; fm++)
            #pragma unroll
            for (int c = 0; c < 8; c++)
                a[fm][c] = *(const bf16x8*)(Ab + fm * 32 * DDIM + c * 16);
    }

    float accS = 0.f;
    const int rb0 = sr * 8 + wv * 2;          // 32-row block indices of this wave
    #pragma unroll 1
    for (int s = 0; s < 8; s++) {             // 8 strips of 32 cols
        const int cb = ck * 8 + s;
        int w0, w1;
        if (mat == 2) { w0 = 1; w1 = 1; }
        else {
            w0 = (cb > rb0)     ? 2 : (cb == rb0)     ? 1 : 0;
            w1 = (cb > rb0 + 1) ? 2 : (cb == rb0 + 1) ? 1 : 0;
            if ((w0 | w1) == 0) continue;     // strip below diagonal
        }
        const int C0 = ck * 256 + s * 32;
        const __bf16* Bb = Yb + (size_t)C0 * DDIM + (size_t)lrow * DDIM + lhalf * 8;

        f32x16 acc[2] = {};
        #pragma unroll
        for (int c = 0; c < 8; c++) {
            bf16x8 b = *(const bf16x8*)(Bb + c * 16);
            acc[0] = __builtin_amdgcn_mfma_f32_32x32x16_bf16(a[0][c], b, acc[0], 0, 0, 0);
            acc[1] = __builtin_amdgcn_mfma_f32_32x32x16_bf16(a[1][c], b, acc[1], 0, 0, 0);
        }

        // ---- epilogue. 32x32 C layout: col=lane&31, row=(reg&3)+8*(reg>>2)+4*(lane>>5)
        const int j = C0 + lrow;
        const float yj = yn[j];
        const float t170 = 170.f - yj;
        #pragma unroll
        for (int fm = 0; fm < 2; fm++) {
            const int wf = fm ? w1 : w0;
            if (wf == 0) continue;
            const int ibase = R0 + fm * 32 + 4 * lhalf;
            float accT = 0.f;
            #pragma unroll
            for (int g = 0; g < 4; g++) {
                const float4 x4 = *(const float4*)(xn + ibase + 8 * g);
                #pragma unroll
                for (int rr = 0; rr < 4; rr++) {
                    const float xv = (rr == 0) ? x4.x : (rr == 1) ? x4.y : (rr == 2) ? x4.z : x4.w;
                    const float lhs = fmaf(-2.f, acc[fm][g * 4 + rr], xv);
                    if (lhs < t170) {                       // d2 < 170
                        float d2 = lhs + yj;
                        float term;
                        if (d2 < 140.f) {
                            const int i = ibase + 8 * g + rr;
                            if (mat < 2 && i == j) continue; // diagonal excluded
                            const float4* xr = (const float4*)(Xf + (size_t)i * DDIM);
                            const float4* yr = (const float4*)(Yf + (size_t)j * DDIM);
                            float dot = 0.f;
                            #pragma unroll 4
                            for (int k = 0; k < 32; k++) {
                                float4 xa = xr[k], yb = yr[k];
                                dot += xa.x * yb.x + xa.y * yb.y + xa.z * yb.z + xa.w * yb.w;
                            }
                            float d2e = fmaxf(xv + yj - 2.f * dot, 0.f);
                            term = __expf(fminf(128.f - 0.5f * d2e, 85.f));
                        } else {
                            term = __expf(128.f - 0.5f * d2);
                        }
                        accT += term;
                    }
                }
            }
            accS += (float)wf * accT;
        }
    }

    // ---- reduce: wave shfl -> LDS(4 floats) -> one plain store per block
    #pragma unroll
    for (int off = 32; off; off >>= 1) accS += __shfl_down(accS, off);
    __shared__ float red[4];
    if (lane == 0) red[wv] = accS;
    __syncthreads();
    if (tid == 0)
        part[bid] = (double)red[0] + (double)red[1] + (double)red[2] + (double)red[3];
}

__global__ void finalize_kernel(const double* __restrict__ part, float* __restrict__ out) {
    __shared__ double red[3][4];
    const int tid = threadIdx.x, w = tid >> 6, lane = tid & 63;
    double sxx = 0.0, syy = 0.0, sxy = 0.0;
    for (int i = tid; i < 528; i += 256)         sxx += part[i];
    for (int i = 528 + tid; i < 1056; i += 256)  syy += part[i];
    for (int i = 1056 + tid; i < NBLK; i += 256) sxy += part[i];
    #pragma unroll
    for (int off = 32; off; off >>= 1) {
        sxx += __shfl_down(sxx, off);
        syy += __shfl_down(syy, off);
        sxy += __shfl_down(sxy, off);
    }
    if (lane == 0) { red[0][w] = sxx; red[1][w] = syy; red[2][w] = sxy; }
    __syncthreads();
    if (tid == 0) {
        const double EM = exp(-128.0);
        double Sxx = (red[0][0] + red[0][1] + red[0][2] + red[0][3]) * EM;
        double Syy = (red[1][0] + red[1][1] + red[1][2] + red[1][3]) * EM;
        double Sxy = (red[2][0] + red[2][1] + red[2][2] + red[2][3]) * EM;
        // Emulate reference fp32 absorption: fl32(N + S_off) - N
        float sumxx = (float)(8192.0 + Sxx);
        float sumyy = (float)(8192.0 + Syy);
        const float scale = 8191.0f / 8192.0f;
        float kxx = (sumxx - 8192.0f) * scale;
        float kyy = (sumyy - 8192.0f) * scale;
        float kxy = (float)(Sxy / (8192.0 * 8192.0));
        out[0] = kxx + kyy - 2.0f * kxy;
    }
}

extern "C" void kernel_launch(void* const* d_in, const int* in_sizes, int n_in,
                              void* d_out, int out_size, void* d_ws, size_t ws_size,
                              hipStream_t stream) {
    const float* z  = (const float*)d_in[0];
    const float* zp = (const float*)d_in[1];
    double* part = (double*)d_ws;                         // 2080 doubles
    float* x2 = (float*)((char*)d_ws + 16896);
    float* y2 = (float*)((char*)d_ws + 49664);
    __bf16* Zb  = (__bf16*)((char*)d_ws + 82432);
    __bf16* Zpb = (__bf16*)((char*)d_ws + 2179584);

    prep_kernel<<<1024, 256, 0, stream>>>(z, zp, x2, y2, Zb, Zpb);
    mmd_gemm<<<NBLK, 256, 0, stream>>>(z, zp, Zb, Zpb, x2, y2, part);
    finalize_kernel<<<1, 256, 0, stream>>>(part, (float*)d_out);
}

// Round 7
// 172.880 us; speedup vs baseline: 1.0933x; 1.0933x over previous
//
#include <hip/hip_runtime.h>
#include <hip/hip_bf16.h>
#include <math.h>

// MMD loss, N=8192 D=128 fp32 in, scalar fp32 out.
// Numerics (validated R1-R6, absmax 0): reference's (sum(Kxx)-trace) cancels to
// exactly 0 in fp32; answer = -2*S_xy/N^2 via emulated fp32 absorption. bf16
// MFMA gives approx d2; d2<140 -> exact fp32 re-dot (rare); 140..170 -> approx
// exp; else skip. All terms scaled e^{+128} -> fp32 accumulators.
//
// R7: persistent multi-tile blocks. Block = 256-row A band (staged once, 64KB)
// x up to 4 col-tiles of 128 (B ping-pong 2x32KB): ASYNC staging for tile t+1
// issued BEFORE computing tile t -> the end-of-tile barrier's vmcnt drain finds
// completed loads (R3's serialized stage->compute phases were the 82.6us wall).
// Wave tiles 64x64 (R4/R5 inner loop, 0.5 ds_read/MFMA), XOR swizzle identical
// to R4 (0 conflicts measured). 1 block/CU (133KB LDS), launch_bounds(512,2)
// -> 256-VGPR budget, no spill (R4/R6 lesson: spill = 77MB WRITE_SIZE).

#define NPTS 8192
#define DDIM 128
#define NBLK 1056   // 272 xx + 272 yy + 512 xy chunks (<=4 tiles of 256x128 each)

typedef __bf16 bf16x8 __attribute__((ext_vector_type(8)));
typedef float f32x4 __attribute__((ext_vector_type(4)));

// async 16B global->LDS (dest = wave-uniform base + lane*16)
#define ASYNC_LD16(gp, lp)                                                        \
    __builtin_amdgcn_global_load_lds(                                             \
        (const __attribute__((address_space(1))) unsigned int*)(gp),              \
        (__attribute__((address_space(3))) unsigned int*)(lp), 16, 0, 0)

// ws layout:
//   0       : double part[1056]  (8448 B per-block partials, scaled e^{+128})
//   16896   : float x2[8192]
//   49664   : float y2[8192]
//   82432   : __bf16 Zb [8192*128]  (2 MB)
//   2179584 : __bf16 Zpb[8192*128]  (2 MB)
__global__ void prep_kernel(const float* __restrict__ Z, const float* __restrict__ Zp,
                            float* __restrict__ x2, float* __restrict__ y2,
                            __bf16* __restrict__ Zb, __bf16* __restrict__ Zpb) {
    const int row = blockIdx.x * 16 + (threadIdx.x >> 4);   // 0..16383
    const int sub = threadIdx.x & 15;
    const float* src; float* nrm; __bf16* dst; int r;
    if (row < NPTS) { src = Z;  nrm = x2; dst = Zb;  r = row; }
    else            { src = Zp; nrm = y2; dst = Zpb; r = row - NPTS; }
    const float4* p = (const float4*)(src + (size_t)r * DDIM) + sub * 2;
    float4 a = p[0], b = p[1];
    float s = a.x*a.x + a.y*a.y + a.z*a.z + a.w*a.w
            + b.x*b.x + b.y*b.y + b.z*b.z + b.w*b.w;
    bf16x8 o = { (__bf16)a.x, (__bf16)a.y, (__bf16)a.z, (__bf16)a.w,
                 (__bf16)b.x, (__bf16)b.y, (__bf16)b.z, (__bf16)b.w };
    *(bf16x8*)(dst + (size_t)r * DDIM + sub * 8) = o;
    #pragma unroll
    for (int off = 8; off; off >>= 1) s += __shfl_down(s, off, 16);
    if (sub == 0) nrm[r] = s;
}

__launch_bounds__(512, 2)
__global__ void mmd_gemm(const float* __restrict__ Z, const float* __restrict__ Zp,
                         const __bf16* __restrict__ Zb, const __bf16* __restrict__ Zpb,
                         const float* __restrict__ x2g, const float* __restrict__ y2g,
                         double* __restrict__ part) {
    // ---- decode bid -> (mat, band, c0, nt): band = 256 rows, col-tiles = 128 cols.
    // Triangles keep col-tiles c >= 2*band (tile fully below diagonal skipped);
    // chunks of <=4 consecutive col-tiles.
    int rem = (int)blockIdx.x;
    int mat = 2, band = 0, c0 = 0, nt = 4;
    bool found = false;
    for (int m = 0; m < 2 && !found; m++) {
        for (int b = 0; b < 32; b++) {
            int ntil = 64 - 2 * b;
            int nch = (ntil + 3) >> 2;
            if (rem < nch) {
                mat = m; band = b; c0 = 2 * b + rem * 4;
                nt = min(4, ntil - rem * 4); found = true; break;
            }
            rem -= nch;
        }
    }
    if (!found) { band = rem >> 4; c0 = (rem & 15) * 4; }   // xy: 32 bands x 16 chunks

    const float*  Xf = (mat == 1) ? Zp  : Z;
    const float*  Yf = (mat == 0) ? Z   : Zp;
    const __bf16* Xb = (mat == 1) ? Zpb : Zb;
    const __bf16* Yb = (mat == 0) ? Zb  : Zpb;
    const float*  xn = (mat == 1) ? y2g : x2g;
    const float*  yn = (mat == 0) ? x2g : y2g;

    __shared__ __bf16 As[256 * DDIM];        // 64 KB, XOR-swizzled 16B chunks
    __shared__ __bf16 Bs[2][128 * DDIM];     // 2 x 32 KB ping-pong
    __shared__ float x2s[256];
    __shared__ float y2s[2][128];
    __shared__ float red[8];

    const int tid = threadIdx.x;
    const int w = tid >> 6, lane = tid & 63;
    const int lr = lane & 15;
    const int q  = lane >> 4;                // 0..3
    const int wm0 = (w >> 1) * 64;           // 4 row-groups x 2 col-groups
    const int wn0 = (w & 1) * 64;

    // ---- stage A band (once) + first B tile; LDS[row][cs] = G[row][cs^(row&15)]
    {
        const __bf16* srcA = Xb + (size_t)band * 256 * DDIM;
        #pragma unroll
        for (int t = 0; t < 8; t++) {
            int row = w * 32 + t * 4 + (lane >> 4);
            int cc = (lane & 15) ^ (row & 15);
            ASYNC_LD16(srcA + (size_t)row * DDIM + cc * 8, (char*)As + w * 8192 + t * 1024);
        }
        const __bf16* srcB = Yb + (size_t)c0 * 128 * DDIM;
        #pragma unroll
        for (int t = 0; t < 4; t++) {
            int row = w * 16 + t * 4 + (lane >> 4);
            int cc = (lane & 15) ^ (row & 15);
            ASYNC_LD16(srcB + (size_t)row * DDIM + cc * 8, (char*)Bs[0] + w * 4096 + t * 1024);
        }
    }
    if (tid < 256)      x2s[tid] = xn[band * 256 + tid];
    else if (tid < 384) y2s[0][tid - 256] = yn[c0 * 128 + (tid - 256)];
    __syncthreads();

    float accS = 0.f;
    for (int t = 0; t < nt; t++) {
        const int buf = t & 1;
        // ---- prefetch next B tile into the other buffer (hidden by compute)
        if (t + 1 < nt) {
            const int cn = c0 + t + 1;
            const __bf16* srcB = Yb + (size_t)cn * 128 * DDIM;
            char* d = (char*)Bs[buf ^ 1];
            #pragma unroll
            for (int tt = 0; tt < 4; tt++) {
                int row = w * 16 + tt * 4 + (lane >> 4);
                int cc = (lane & 15) ^ (row & 15);
                ASYNC_LD16(srcB + (size_t)row * DDIM + cc * 8, d + w * 4096 + tt * 1024);
            }
            if (tid < 128) y2s[buf ^ 1][tid] = yn[cn * 128 + tid];
        }

        // ---- MFMA: wave tile 64x64, 4x4 frags of 16x16x32 (R5 liveness order)
        f32x4 acc[4][4] = {};
        const char* Bbase = (const char*)Bs[buf];
        #pragma unroll
        for (int ks = 0; ks < 4; ks++) {
            const int chunk = ks * 4 + q;
            bf16x8 bfr[4];
            #pragma unroll
            for (int f = 0; f < 4; f++) {
                int rb = wn0 + f * 16 + lr;
                bfr[f] = *(const bf16x8*)(Bbase + rb * 256 + ((chunk ^ lr) * 16));
            }
            #pragma unroll
            for (int fm = 0; fm < 4; fm++) {
                int ra = wm0 + fm * 16 + lr;
                bf16x8 afr = *(const bf16x8*)((const char*)As + ra * 256 + ((chunk ^ lr) * 16));
                #pragma unroll
                for (int fn = 0; fn < 4; fn++)
                    acc[fm][fn] = __builtin_amdgcn_mfma_f32_16x16x32_bf16(
                        afr, bfr[fn], acc[fm][fn], 0, 0, 0);
            }
        }

        // ---- epilogue. C/D: col=lane&15, row=q*4+reg [m89/m91]
        const int c = c0 + t;
        const bool straddle = (mat < 2) && (c <= 2 * band + 1); // tile touches diagonal
        float t170[4], syv[4];
        #pragma unroll
        for (int fn = 0; fn < 4; fn++) {
            float s = y2s[buf][wn0 + fn * 16 + lr];
            syv[fn] = s; t170[fn] = 170.f - s;
        }
        float tileS = 0.f;
        #pragma unroll
        for (int fm = 0; fm < 4; fm++) {
            const float4 x4 = *(const float4*)&x2s[wm0 + fm * 16 + q * 4];
            #pragma unroll
            for (int r = 0; r < 4; r++) {
                const float xvr = (r == 0) ? x4.x : (r == 1) ? x4.y : (r == 2) ? x4.z : x4.w;
                const int ci = wm0 + fm * 16 + q * 4 + r;
                #pragma unroll
                for (int fn = 0; fn < 4; fn++) {
                    float lhs = fmaf(-2.f, acc[fm][fn][r], xvr);   // d2 - sy
                    if (lhs < t170[fn]) {                          // d2 < 170
                        const int cj = wn0 + fn * 16 + lr;
                        const int gi = band * 256 + ci, gj = c * 128 + cj;
                        if (straddle && gj <= gi) continue;        // lower tri + diag
                        float d2 = lhs + syv[fn];
                        float term;
                        if (d2 < 140.f) {
                            // exact fp32 re-dot (rare)
                            const float4* xr = (const float4*)(Xf + (size_t)gi * DDIM);
                            const float4* yr = (const float4*)(Yf + (size_t)gj * DDIM);
                            float dot = 0.f;
                            #pragma unroll 4
                            for (int k = 0; k < 32; k++) {
                                float4 xa = xr[k], yb = yr[k];
                                dot += xa.x * yb.x + xa.y * yb.y + xa.z * yb.z + xa.w * yb.w;
                            }
                            float d2e = fmaxf(xvr + syv[fn] - 2.f * dot, 0.f);
                            term = __expf(fminf(128.f - 0.5f * d2e, 85.f));
                        } else {
                            term = __expf(128.f - 0.5f * d2);
                        }
                        tileS += term;
                    }
                }
            }
        }
        accS += (mat == 2) ? tileS : 2.f * tileS;   // triangle mats: mirror weight 2

        __syncthreads();   // publish B(t+1)/y2s(t+1); everyone done with buf
    }

    // ---- reduce: wave shfl -> LDS -> ONE plain store per block
    #pragma unroll
    for (int off = 32; off; off >>= 1) accS += __shfl_down(accS, off);
    if (lane == 0) red[w] = accS;
    __syncthreads();
    if (tid == 0) {
        double tot = 0.0;
        #pragma unroll
        for (int i = 0; i < 8; i++) tot += (double)red[i];
        part[blockIdx.x] = tot;
    }
}

__global__ void finalize_kernel(const double* __restrict__ part, float* __restrict__ out) {
    __shared__ double red[3][4];
    const int tid = threadIdx.x, w = tid >> 6, lane = tid & 63;
    double sxx = 0.0, syy = 0.0, sxy = 0.0;
    for (int i = tid; i < 272; i += 256)         sxx += part[i];
    for (int i = 272 + tid; i < 544; i += 256)   syy += part[i];
    for (int i = 544 + tid; i < NBLK; i += 256)  sxy += part[i];
    #pragma unroll
    for (int off = 32; off; off >>= 1) {
        sxx += __shfl_down(sxx, off);
        syy += __shfl_down(syy, off);
        sxy += __shfl_down(sxy, off);
    }
    if (lane == 0) { red[0][w] = sxx; red[1][w] = syy; red[2][w] = sxy; }
    __syncthreads();
    if (tid == 0) {
        const double EM = exp(-128.0);
        double Sxx = (red[0][0] + red[0][1] + red[0][2] + red[0][3]) * EM;
        double Syy = (red[1][0] + red[1][1] + red[1][2] + red[1][3]) * EM;
        double Sxy = (red[2][0] + red[2][1] + red[2][2] + red[2][3]) * EM;
        // Emulate reference fp32 absorption: fl32(N + S_off) - N
        float sumxx = (float)(8192.0 + Sxx);
        float sumyy = (float)(8192.0 + Syy);
        const float scale = 8191.0f / 8192.0f;
        float kxx = (sumxx - 8192.0f) * scale;
        float kyy = (sumyy - 8192.0f) * scale;
        float kxy = (float)(Sxy / (8192.0 * 8192.0));
        out[0] = kxx + kyy - 2.0f * kxy;
    }
}

extern "C" void kernel_launch(void* const* d_in, const int* in_sizes, int n_in,
                              void* d_out, int out_size, void* d_ws, size_t ws_size,
                              hipStream_t stream) {
    const float* z  = (const float*)d_in[0];
    const float* zp = (const float*)d_in[1];
    double* part = (double*)d_ws;                         // 1056 doubles
    float* x2 = (float*)((char*)d_ws + 16896);
    float* y2 = (float*)((char*)d_ws + 49664);
    __bf16* Zb  = (__bf16*)((char*)d_ws + 82432);
    __bf16* Zpb = (__bf16*)((char*)d_ws + 2179584);

    prep_kernel<<<1024, 256, 0, stream>>>(z, zp, x2, y2, Zb, Zpb);
    mmd_gemm<<<NBLK, 512, 0, stream>>>(z, zp, Zb, Zpb, x2, y2, part);
    finalize_kernel<<<1, 256, 0, stream>>>(part, (float*)d_out);
}